// Round 39
// baseline (110.938 us; speedup 1.0000x reference)
//
#include <hip/hip_runtime.h>
#include <hip/hip_bf16.h>

#define TOKENS 2048
#define FDIM 512
#define HDIM 2048
#define NEXP 8
#define PI_F 3.14159265358979323846f

typedef __attribute__((ext_vector_type(8))) short bf16x8;
typedef __attribute__((ext_vector_type(4))) float f32x4;

__device__ __forceinline__ unsigned short f2bf(float f) {
  unsigned int u = __float_as_uint(f);
  unsigned int r = (u + 0x7fffu + ((u >> 16) & 1u)) >> 16;
  return (unsigned short)r;
}

__device__ __forceinline__ void gload16(const void* g, void* l) {
  __builtin_amdgcn_global_load_lds(
      (const __attribute__((address_space(1))) unsigned int*)g,
      (__attribute__((address_space(3))) unsigned int*)l, 16, 0, 0);
}

// ---------- pack body: one 64x32 tile (r14-proven) ----------
template<int K, int N>
__device__ __forceinline__ void pack_w_body64(
    const float* __restrict__ Wr, const float* __restrict__ Wi,
    short* __restrict__ Wp, int b, float (*tr)[33], float (*ti)[33])
{
  constexpr int NT_ = N / 32;
  int per_e = (K / 64) * NT_;
  int e = b / per_e;
  int rem = b % per_e;
  int k0 = (rem / NT_) * 64, n0 = (rem % NT_) * 32;
  int tid = threadIdx.x;
  int row = tid >> 2, c8 = (tid & 3) * 8;
  const float* wr = Wr + ((size_t)e * K + k0 + row) * N + n0 + c8;
  const float* wi = Wi + ((size_t)e * K + k0 + row) * N + n0 + c8;
  float4 a0 = *(const float4*)(wr);
  float4 a1 = *(const float4*)(wr + 4);
  float4 b0 = *(const float4*)(wi);
  float4 b1 = *(const float4*)(wi + 4);
  *(float4*)&tr[row][c8] = a0;  *(float4*)&tr[row][c8 + 4] = a1;
  *(float4*)&ti[row][c8] = b0;  *(float4*)&ti[row][c8 + 4] = b1;
  __syncthreads();
  int nl = tid >> 3, k8 = (tid & 7) * 8;
  unsigned short pr[8], pi[8];
  #pragma unroll
  for (int j = 0; j < 8; ++j) {
    pr[j] = f2bf(tr[k8 + j][nl]);
    pi[j] = f2bf(ti[k8 + j][nl]);
  }
  size_t d0 = (((size_t)e * 2 + 0) * N + n0 + nl) * K + k0 + k8;
  size_t d1 = (((size_t)e * 2 + 1) * N + n0 + nl) * K + k0 + k8;
  *(int4*)(Wp + d0) = *(const int4*)pr;
  *(int4*)(Wp + d1) = *(const int4*)pi;
}

// ---------- pack body: TWO k-adjacent 64x32 tiles (r18-proven) ----------
template<int K, int N>
__device__ __forceinline__ void pack_w2x(
    const float* __restrict__ Wr, const float* __restrict__ Wi,
    short* __restrict__ Wp, int b, float (*tr)[33], float (*ti)[33])
{
  constexpr int NT_ = N / 32;
  int per_e = (K / 128) * NT_;
  int e = b / per_e;
  int rem = b % per_e;
  int k0 = (rem / NT_) * 128, n0 = (rem % NT_) * 32;
  int tid = threadIdx.x;
  int row = tid >> 2, c8 = (tid & 3) * 8;
  const float* wr = Wr + ((size_t)e * K + k0 + row) * N + n0 + c8;
  const float* wi = Wi + ((size_t)e * K + k0 + row) * N + n0 + c8;
  const float* wr1 = wr + (size_t)64 * N;
  const float* wi1 = wi + (size_t)64 * N;
  float4 a00 = *(const float4*)(wr);
  float4 a01 = *(const float4*)(wr + 4);
  float4 b00 = *(const float4*)(wi);
  float4 b01 = *(const float4*)(wi + 4);
  float4 a10 = *(const float4*)(wr1);
  float4 a11 = *(const float4*)(wr1 + 4);
  float4 b10 = *(const float4*)(wi1);
  float4 b11 = *(const float4*)(wi1 + 4);
  int nl = tid >> 3, k8 = (tid & 7) * 8;
  size_t d0 = (((size_t)e * 2 + 0) * N + n0 + nl) * K + k0 + k8;
  size_t d1 = (((size_t)e * 2 + 1) * N + n0 + nl) * K + k0 + k8;
  *(float4*)&tr[row][c8] = a00;  *(float4*)&tr[row][c8 + 4] = a01;
  *(float4*)&ti[row][c8] = b00;  *(float4*)&ti[row][c8 + 4] = b01;
  __syncthreads();
  {
    unsigned short pr[8], pi[8];
    #pragma unroll
    for (int j = 0; j < 8; ++j) {
      pr[j] = f2bf(tr[k8 + j][nl]);
      pi[j] = f2bf(ti[k8 + j][nl]);
    }
    *(int4*)(Wp + d0) = *(const int4*)pr;
    *(int4*)(Wp + d1) = *(const int4*)pi;
  }
  __syncthreads();
  *(float4*)&tr[row][c8] = a10;  *(float4*)&tr[row][c8 + 4] = a11;
  *(float4*)&ti[row][c8] = b10;  *(float4*)&ti[row][c8 + 4] = b11;
  __syncthreads();
  {
    unsigned short pr[8], pi[8];
    #pragma unroll
    for (int j = 0; j < 8; ++j) {
      pr[j] = f2bf(tr[k8 + j][nl]);
      pi[j] = f2bf(ti[k8 + j][nl]);
    }
    *(int4*)(Wp + d0 + 64) = *(const int4*)pr;
    *(int4*)(Wp + d1 + 64) = *(const int4*)pi;
  }
}

// ---- kernel A: route (256) + pack_x token-order (1024) + pack W1 (2048) ----
__global__ __launch_bounds__(256, 2) void route_packx_w1_kernel(
    const float* __restrict__ xr, const float* __restrict__ xi,
    int* __restrict__ idx,
    short* __restrict__ Ar, short* __restrict__ Ai,
    const float* __restrict__ Wr1, const float* __restrict__ Wi1,
    short* __restrict__ W1p)
{
  __shared__ float tr[64][33], ti[64][33];
  int bid = blockIdx.x;
  if (bid < 256) {
    // route: 8 tokens per block, width-32 reduce (r7-proven)
    int tid = threadIdx.x;
    int t = bid * 8 + (tid >> 5);
    int l = tid & 31;
    const float* r  = xr + (size_t)t * FDIM;
    const float* im = xi + (size_t)t * FDIM;
    float sc = 0.f, ss = 0.f;
    #pragma unroll
    for (int p = 0; p < 4; ++p) {
      int f = p * 128 + l * 4;
      float4 a4 = *(const float4*)(r + f);
      float4 b4 = *(const float4*)(im + f);
      float av[4] = {a4.x, a4.y, a4.z, a4.w};
      float bv[4] = {b4.x, b4.y, b4.z, b4.w};
      #pragma unroll
      for (int j = 0; j < 4; ++j) {
        float h2 = av[j] * av[j] + bv[j] * bv[j];
        if (h2 > 0.f) {
          float rs = rsqrtf(h2);
          sc += av[j] * rs;
          ss += bv[j] * rs;
        } else {
          sc += 1.f;   // atan2(0,0)=0 -> cos=1, sin=0
        }
      }
    }
    #pragma unroll
    for (int off = 16; off > 0; off >>= 1) {
      sc += __shfl_down(sc, off, 32);
      ss += __shfl_down(ss, off, 32);
    }
    if (l == 0) {
      float phase = atan2f(ss, sc);
      float norm = (phase + PI_F) / (2.f * PI_F);
      int e = (int)floorf(norm * (float)NEXP);
      e = min(max(e, 0), NEXP - 1);
      idx[t] = e;
    }
  } else if (bid < 256 + 1024) {
    // pack x -> bf16 planes in TOKEN order (no perm dependency)
    int gid = (bid - 256) * 256 + threadIdx.x;   // 1024 blocks x 256
    int i = gid >> 7;
    int c4 = (gid & 127) * 4;
    float4 r = *(const float4*)(xr + (size_t)i * FDIM + c4);
    float4 m = *(const float4*)(xi + (size_t)i * FDIM + c4);
    unsigned short orr[4] = { f2bf(r.x), f2bf(r.y), f2bf(r.z), f2bf(r.w) };
    unsigned short oii[4] = { f2bf(m.x), f2bf(m.y), f2bf(m.z), f2bf(m.w) };
    *(int2*)(Ar + (size_t)i * FDIM + c4) = *(const int2*)orr;
    *(int2*)(Ai + (size_t)i * FDIM + c4) = *(const int2*)oii;
  } else {
    pack_w2x<FDIM, HDIM>(Wr1, Wi1, W1p, bid - 1280, tr, ti);
  }
}

// deterministic scatter (r19-proven): computes counts + offs + perm + rexp
__global__ __launch_bounds__(256) void scatter_kernel(
    const int* __restrict__ idx, int* __restrict__ counts,
    int* __restrict__ offs, int* __restrict__ perm, int* __restrict__ rexp)
{
  __shared__ int base_e[NEXP];
  __shared__ int totals[NEXP];
  __shared__ int tcnt[256][NEXP];
  int tid = threadIdx.x;
  int t0 = tid * 8;
  int eo[8];
  int loc[NEXP];
  #pragma unroll
  for (int e = 0; e < NEXP; ++e) loc[e] = 0;
  #pragma unroll
  for (int j = 0; j < 8; ++j) { eo[j] = idx[t0 + j]; loc[eo[j]]++; }
  #pragma unroll
  for (int e = 0; e < NEXP; ++e) tcnt[tid][e] = loc[e];
  __syncthreads();
  if (tid < NEXP) {
    int e = tid, run = 0;
    for (int i = 0; i < 256; ++i) { int v = tcnt[i][e]; tcnt[i][e] = run; run += v; }
    totals[e] = run;
    counts[e] = run;
  }
  __syncthreads();
  if (tid == 0) {
    int acc = 0;
    for (int e = 0; e < NEXP; ++e) { base_e[e] = acc; offs[e] = acc; acc += totals[e]; }
  }
  __syncthreads();
  #pragma unroll
  for (int e = 0; e < NEXP; ++e) loc[e] = base_e[e] + tcnt[tid][e];
  #pragma unroll
  for (int j = 0; j < 8; ++j) {
    int e = eo[j];
    int pos = loc[e]++;
    perm[pos] = t0 + j;
    rexp[pos] = e;
  }
}

// ---------------- plane-separated complex MFMA grouped GEMM body ------------
// r14-exact schedule + T5 setprio (r24-proven): BM=64 x BNc=64, BK=32, 4 waves,
// 2-buffer 32KB LDS, fully-drained single-__syncthreads-per-step loop.
template<int LDK, int NC, int NX, int NSPLIT, bool IS_L1>
__device__ __forceinline__ void gemm_body(
    int gbid, int xcd, short* AsB, short* WsB,
    const short* __restrict__ Apr, const short* __restrict__ Api,
    const short* __restrict__ Wp,
    const int* __restrict__ counts, const int* __restrict__ offs,
    const int* __restrict__ perm,
    const float* __restrict__ bre, const float* __restrict__ bim,
    const float* __restrict__ mb,
    short* __restrict__ Or, short* __restrict__ Oi,
    unsigned int* __restrict__ P)
{
  constexpr int PBE = NX * 8 * NSPLIT;       // blocks per expert
  constexpr int KCH = LDK / NSPLIT;          // K-chunk
  constexpr int KT = KCH / 32;               // steps
  int virt = xcd * PBE + (gbid >> 3);        // per-XCD expert affinity
  int e = virt / PBE, rem = virt % PBE;
  int x = rem % NX;
  int q = rem / NX;
  int y = q & 7, s = q >> 3;                 // s in [0, NSPLIT)
  int cnt = counts[e];
  int row0 = y * 64;
  if (row0 >= cnt) return;
  int base = offs[e];
  int n0c = x * 64;
  int kbase = s * KCH;

  int tid = threadIdx.x;
  int lane = tid & 63;
  int w = tid >> 6, wm = w >> 1, wn = w & 1;
  int lr = lane & 15, g = lane >> 4;
  int ssw = g ^ ((lr >> 1) & 3);             // swizzled 16B slot for reads

  int srl = tid >> 2, slt = tid & 3;
  int sc = (slt ^ ((srl >> 1) & 3)) * 16;    // pre-swizzled source byte offset
  int arow = min(row0 + srl, cnt - 1);
  size_t asrc;
  if constexpr (IS_L1) asrc = (size_t)perm[base + arow] * LDK + kbase;  // gather
  else                 asrc = (size_t)(base + arow) * LDK + kbase;      // compact
  const char* pAr = (const char*)(Apr + asrc) + sc;
  const char* pAi = (const char*)(Api + asrc) + sc;
  const short* We = Wp + (size_t)e * 2 * NC * LDK;
  const char* pW0 = (const char*)(We + (size_t)(n0c + srl) * LDK + kbase) + sc;
  const char* pW1 = (const char*)(We + ((size_t)NC + n0c + srl) * LDK + kbase) + sc;

  auto STAGE = [&](int buf, int t) {         // 4 gload16 per thread
    char* ab = (char*)AsB + buf * 8192;
    gload16(pAr + t * 64, ab + tid * 16);
    gload16(pAi + t * 64, ab + 4096 + tid * 16);
    char* wb = (char*)WsB + buf * 8192;
    gload16(pW0 + t * 64, wb + tid * 16);
    gload16(pW1 + t * 64, wb + 4096 + tid * 16);
  };

  f32x4 accr[2][2], acci[2][2];
  #pragma unroll
  for (int m = 0; m < 2; ++m)
    #pragma unroll
    for (int n = 0; n < 2; ++n) { accr[m][n] = 0.f; acci[m][n] = 0.f; }

  const bf16x8 SGN = {(short)0x8000, (short)0x8000, (short)0x8000, (short)0x8000,
                      (short)0x8000, (short)0x8000, (short)0x8000, (short)0x8000};

  auto COMPUTE = [&](int buf) {
    const short* Ab = AsB + buf * 4096;
    const short* Wb = WsB + buf * 4096;
    bf16x8 ar[2], ai[2], wr[2], wi[2], wni[2];
    #pragma unroll
    for (int m = 0; m < 2; ++m) {
      int off = (wm * 32 + m * 16 + lr) * 32 + ssw * 8;
      ar[m] = *(const bf16x8*)(Ab + off);
      ai[m] = *(const bf16x8*)(Ab + 2048 + off);
    }
    #pragma unroll
    for (int n = 0; n < 2; ++n) {
      int offw = (wn * 32 + n * 16 + lr) * 32 + ssw * 8;
      wr[n] = *(const bf16x8*)(Wb + offw);
      wi[n] = *(const bf16x8*)(Wb + 2048 + offw);
      wni[n] = wi[n] ^ SGN;
    }
    __builtin_amdgcn_s_setprio(1);           // T5: favor MFMA waves (hint only)
    #pragma unroll
    for (int m = 0; m < 2; ++m)
      #pragma unroll
      for (int n = 0; n < 2; ++n) {
        accr[m][n] = __builtin_amdgcn_mfma_f32_16x16x32_bf16(ar[m], wr[n],  accr[m][n], 0, 0, 0);
        accr[m][n] = __builtin_amdgcn_mfma_f32_16x16x32_bf16(ai[m], wni[n], accr[m][n], 0, 0, 0);
        acci[m][n] = __builtin_amdgcn_mfma_f32_16x16x32_bf16(ar[m], wi[n],  acci[m][n], 0, 0, 0);
        acci[m][n] = __builtin_amdgcn_mfma_f32_16x16x32_bf16(ai[m], wr[n],  acci[m][n], 0, 0, 0);
      }
    __builtin_amdgcn_s_setprio(0);
  };

  STAGE(0, 0);
  int cur = 0;
  for (int t = 0; t < KT; ++t) {
    __syncthreads();                         // full fence: stage of `cur` drained
    if (t + 1 < KT) STAGE(cur ^ 1, t + 1);   // prefetch overlaps COMPUTE(cur)
    COMPUTE(cur);
    cur ^= 1;
  }

  // epilogue
  #pragma unroll
  for (int m = 0; m < 2; ++m) {
    #pragma unroll
    for (int qq = 0; qq < 4; ++qq) {
      int row = row0 + wm * 32 + m * 16 + g * 4 + qq;
      if (row >= cnt) continue;
      #pragma unroll
      for (int n = 0; n < 2; ++n) {
        int c = n0c + wn * 32 + n * 16 + lr;
        if constexpr (IS_L1) {
          float hr = accr[m][n][qq] + bre[e * NC + c];
          float hi = acci[m][n][qq] + bim[e * NC + c];
          float s2 = hr * hr + hi * hi + 1e-10f;
          float rr = __frsqrt_rn(s2);
          float amp = s2 * rr;
          float scl = fmaxf(amp + mb[e * NC + c], 0.f) * rr;
          Or[(size_t)(base + row) * NC + c] = (short)f2bf(hr * scl);
          Oi[(size_t)(base + row) * NC + c] = (short)f2bf(hi * scl);
        } else {
          // packed bf16 partial: lo16 = re, hi16 = im
          unsigned pv = (unsigned)f2bf(accr[m][n][qq])
                      | ((unsigned)f2bf(acci[m][n][qq]) << 16);
          P[((size_t)s * TOKENS + base + row) * 512 + c] = pv;
        }
      }
    }
  }
}

// ---- kernel B (r24-exact): gemm1 (bid%3==0) + pack W2 (4096) ----
__global__ __launch_bounds__(256) void gemm1_packw2_kernel(
    const short* __restrict__ A1r, const short* __restrict__ A1i,
    const short* __restrict__ W1p,
    const int* __restrict__ counts, const int* __restrict__ offs,
    const int* __restrict__ perm,
    const float* __restrict__ br1, const float* __restrict__ bi1,
    const float* __restrict__ mb,
    short* __restrict__ A2r, short* __restrict__ A2i,
    const float* __restrict__ Wr2, const float* __restrict__ Wi2,
    short* __restrict__ W2p)
{
  __shared__ __align__(16) short As[2][2][64][32];   // 16KB
  __shared__ __align__(16) short Ws[2][2][64][32];   // 16KB
  int bid = blockIdx.x;
  int r3 = bid % 3;
  if (r3 == 0) {
    int g = bid / 3;                         // 0..2047, (bid&7, g>>3) bijective
    gemm_body<FDIM, HDIM, 32, 1, true>(g, bid & 7, &As[0][0][0][0], &Ws[0][0][0][0],
        A1r, A1i, W1p, counts, offs, perm, br1, bi1, mb, A2r, A2i, nullptr);
  } else {
    int pb = (bid / 3) * 2 + (r3 - 1);       // 0..4095 bijective
    float (*tr)[33] = (float (*)[33])&As[0][0][0][0];   // 8448B <= 16KB
    float (*ti)[33] = (float (*)[33])&Ws[0][0][0][0];
    pack_w_body64<HDIM, FDIM>(Wr2, Wi2, W2p, pb, tr, ti);
  }
}

// ---------------- standalone gemm2: split-K = 4 (r19-proven) ----------------
__global__ __launch_bounds__(256) void gemm2_kernel(
    const short* __restrict__ A2r, const short* __restrict__ A2i,
    const short* __restrict__ W2p,
    const int* __restrict__ counts, const int* __restrict__ offs,
    unsigned int* __restrict__ P)
{
  __shared__ __align__(16) short As[2][2][64][32];
  __shared__ __align__(16) short Ws[2][2][64][32];
  int bid = blockIdx.x;
  gemm_body<HDIM, FDIM, 8, 4, false>(bid, bid & 7, &As[0][0][0][0], &Ws[0][0][0][0],
      A2r, A2i, W2p, counts, offs, nullptr, nullptr, nullptr, nullptr,
      nullptr, nullptr, P);
}

// ---------------- split-K finalize (4 bf16-packed partials) ----------------
__global__ __launch_bounds__(256) void finalize_kernel(
    const unsigned int* __restrict__ P, const float* __restrict__ br2,
    const float* __restrict__ bi2, const int* __restrict__ perm,
    const int* __restrict__ rexp, float* __restrict__ out)
{
  int gid = blockIdx.x * 256 + threadIdx.x;   // 2048 * 128
  int i = gid >> 7;
  int c4 = (gid & 127) * 4;
  float sr[4] = {0.f, 0.f, 0.f, 0.f}, si[4] = {0.f, 0.f, 0.f, 0.f};
  #pragma unroll
  for (int s = 0; s < 4; ++s) {
    uint4 u = *(const uint4*)(P + ((size_t)s * TOKENS + i) * 512 + c4);
    unsigned uv[4] = {u.x, u.y, u.z, u.w};
    #pragma unroll
    for (int j = 0; j < 4; ++j) {
      sr[j] += __uint_as_float(uv[j] << 16);
      si[j] += __uint_as_float(uv[j] & 0xFFFF0000u);
    }
  }
  int e = rexp[i], tok = perm[i];
  float4 br = *(const float4*)(br2 + e * FDIM + c4);
  float4 bi = *(const float4*)(bi2 + e * FDIM + c4);
  float4 vr = {sr[0] + br.x, sr[1] + br.y, sr[2] + br.z, sr[3] + br.w};
  float4 vi = {si[0] + bi.x, si[1] + bi.y, si[2] + bi.z, si[3] + bi.w};
  *(float4*)(out + (size_t)tok * FDIM + c4) = vr;
  *(float4*)(out + (size_t)TOKENS * FDIM + (size_t)tok * FDIM + c4) = vi;
}

extern "C" void kernel_launch(void* const* d_in, const int* in_sizes, int n_in,
                              void* d_out, int out_size, void* d_ws, size_t ws_size,
                              hipStream_t stream)
{
  const float* xr  = (const float*)d_in[0];
  const float* xi  = (const float*)d_in[1];
  const float* Wr1 = (const float*)d_in[2];
  const float* Wi1 = (const float*)d_in[3];
  const float* br1 = (const float*)d_in[4];
  const float* bi1 = (const float*)d_in[5];
  const float* mb  = (const float*)d_in[6];
  const float* Wr2 = (const float*)d_in[7];
  const float* Wi2 = (const float*)d_in[8];
  const float* br2 = (const float*)d_in[9];
  const float* bi2 = (const float*)d_in[10];
  float* out = (float*)d_out;

  char* ws = (char*)d_ws;
  int* counts = (int*)(ws + 0);
  int* offs   = (int*)(ws + 64);
  int* idx    = (int*)(ws + 128);
  int* perm   = (int*)(ws + 8320);
  int* rexp   = (int*)(ws + 16512);

  size_t off = 32768;
  short* A1r = (short*)(ws + off); off += (size_t)TOKENS * FDIM * 2;
  short* A1i = (short*)(ws + off); off += (size_t)TOKENS * FDIM * 2;
  short* A2r = (short*)(ws + off); off += (size_t)TOKENS * HDIM * 2;
  short* A2i = (short*)(ws + off); off += (size_t)TOKENS * HDIM * 2;
  short* W1p = (short*)(ws + off); off += (size_t)NEXP * 2 * HDIM * FDIM * 2;
  short* W2p = (short*)(ws + off); off += (size_t)NEXP * 2 * FDIM * HDIM * 2;
  unsigned int* P = (unsigned int*)(ws + off);   // 4 x 2048 x 512 uints = 16MB

  // A: route (256) + pack_x token-order (1024) + W1 pack (2048), all parallel
  route_packx_w1_kernel<<<256 + 1024 + 2048, 256, 0, stream>>>(
      xr, xi, idx, A1r, A1i, Wr1, Wi1, W1p);
  // scatter computes counts + offs + perm + rexp from idx
  scatter_kernel<<<1, 256, 0, stream>>>(idx, counts, offs, perm, rexp);

  // B: gemm1 (perm-gather A1, bias+ModReLU fused) concurrent with W2 pack
  gemm1_packw2_kernel<<<6144, 256, 0, stream>>>(
      A1r, A1i, W1p, counts, offs, perm, br1, bi1, mb, A2r, A2i, Wr2, Wi2, W2p);
  // layer2: K=2048 split 4x512 -> packed bf16 partials
  gemm2_kernel<<<2048, 256, 0, stream>>>(A2r, A2i, W2p, counts, offs, P);

  finalize_kernel<<<TOKENS * 128 / 256, 256, 0, stream>>>(
      P, br2, bi2, perm, rexp, out);
}

// Round 40
// 108.197 us; speedup vs baseline: 1.0253x; 1.0253x over previous
//
#include <hip/hip_runtime.h>
#include <hip/hip_bf16.h>

#define TOKENS 2048
#define FDIM 512
#define HDIM 2048
#define NEXP 8
#define PI_F 3.14159265358979323846f

typedef __attribute__((ext_vector_type(8))) short bf16x8;
typedef __attribute__((ext_vector_type(4))) float f32x4;

__device__ __forceinline__ unsigned short f2bf(float f) {
  unsigned int u = __float_as_uint(f);
  unsigned int r = (u + 0x7fffu + ((u >> 16) & 1u)) >> 16;
  return (unsigned short)r;
}

__device__ __forceinline__ void gload16(const void* g, void* l) {
  __builtin_amdgcn_global_load_lds(
      (const __attribute__((address_space(1))) unsigned int*)g,
      (__attribute__((address_space(3))) unsigned int*)l, 16, 0, 0);
}

// ---------- pack body: one 64x32 tile (r14-proven) ----------
template<int K, int N>
__device__ __forceinline__ void pack_w_body64(
    const float* __restrict__ Wr, const float* __restrict__ Wi,
    short* __restrict__ Wp, int b, float (*tr)[33], float (*ti)[33])
{
  constexpr int NT_ = N / 32;
  int per_e = (K / 64) * NT_;
  int e = b / per_e;
  int rem = b % per_e;
  int k0 = (rem / NT_) * 64, n0 = (rem % NT_) * 32;
  int tid = threadIdx.x;
  int row = tid >> 2, c8 = (tid & 3) * 8;
  const float* wr = Wr + ((size_t)e * K + k0 + row) * N + n0 + c8;
  const float* wi = Wi + ((size_t)e * K + k0 + row) * N + n0 + c8;
  float4 a0 = *(const float4*)(wr);
  float4 a1 = *(const float4*)(wr + 4);
  float4 b0 = *(const float4*)(wi);
  float4 b1 = *(const float4*)(wi + 4);
  *(float4*)&tr[row][c8] = a0;  *(float4*)&tr[row][c8 + 4] = a1;
  *(float4*)&ti[row][c8] = b0;  *(float4*)&ti[row][c8 + 4] = b1;
  __syncthreads();
  int nl = tid >> 3, k8 = (tid & 7) * 8;
  unsigned short pr[8], pi[8];
  #pragma unroll
  for (int j = 0; j < 8; ++j) {
    pr[j] = f2bf(tr[k8 + j][nl]);
    pi[j] = f2bf(ti[k8 + j][nl]);
  }
  size_t d0 = (((size_t)e * 2 + 0) * N + n0 + nl) * K + k0 + k8;
  size_t d1 = (((size_t)e * 2 + 1) * N + n0 + nl) * K + k0 + k8;
  *(int4*)(Wp + d0) = *(const int4*)pr;
  *(int4*)(Wp + d1) = *(const int4*)pi;
}

// ---------- pack body: TWO k-adjacent 64x32 tiles (r18-proven) ----------
template<int K, int N>
__device__ __forceinline__ void pack_w2x(
    const float* __restrict__ Wr, const float* __restrict__ Wi,
    short* __restrict__ Wp, int b, float (*tr)[33], float (*ti)[33])
{
  constexpr int NT_ = N / 32;
  int per_e = (K / 128) * NT_;
  int e = b / per_e;
  int rem = b % per_e;
  int k0 = (rem / NT_) * 128, n0 = (rem % NT_) * 32;
  int tid = threadIdx.x;
  int row = tid >> 2, c8 = (tid & 3) * 8;
  const float* wr = Wr + ((size_t)e * K + k0 + row) * N + n0 + c8;
  const float* wi = Wi + ((size_t)e * K + k0 + row) * N + n0 + c8;
  const float* wr1 = wr + (size_t)64 * N;
  const float* wi1 = wi + (size_t)64 * N;
  float4 a00 = *(const float4*)(wr);
  float4 a01 = *(const float4*)(wr + 4);
  float4 b00 = *(const float4*)(wi);
  float4 b01 = *(const float4*)(wi + 4);
  float4 a10 = *(const float4*)(wr1);
  float4 a11 = *(const float4*)(wr1 + 4);
  float4 b10 = *(const float4*)(wi1);
  float4 b11 = *(const float4*)(wi1 + 4);
  int nl = tid >> 3, k8 = (tid & 7) * 8;
  size_t d0 = (((size_t)e * 2 + 0) * N + n0 + nl) * K + k0 + k8;
  size_t d1 = (((size_t)e * 2 + 1) * N + n0 + nl) * K + k0 + k8;
  *(float4*)&tr[row][c8] = a00;  *(float4*)&tr[row][c8 + 4] = a01;
  *(float4*)&ti[row][c8] = b00;  *(float4*)&ti[row][c8 + 4] = b01;
  __syncthreads();
  {
    unsigned short pr[8], pi[8];
    #pragma unroll
    for (int j = 0; j < 8; ++j) {
      pr[j] = f2bf(tr[k8 + j][nl]);
      pi[j] = f2bf(ti[k8 + j][nl]);
    }
    *(int4*)(Wp + d0) = *(const int4*)pr;
    *(int4*)(Wp + d1) = *(const int4*)pi;
  }
  __syncthreads();
  *(float4*)&tr[row][c8] = a10;  *(float4*)&tr[row][c8 + 4] = a11;
  *(float4*)&ti[row][c8] = b10;  *(float4*)&ti[row][c8 + 4] = b11;
  __syncthreads();
  {
    unsigned short pr[8], pi[8];
    #pragma unroll
    for (int j = 0; j < 8; ++j) {
      pr[j] = f2bf(tr[k8 + j][nl]);
      pi[j] = f2bf(ti[k8 + j][nl]);
    }
    *(int4*)(Wp + d0 + 64) = *(const int4*)pr;
    *(int4*)(Wp + d1 + 64) = *(const int4*)pi;
  }
}

// ---- kernel A: route (256) + pack_x token-order (1024) + pack W1 (2048) ----
__global__ __launch_bounds__(256, 2) void route_packx_w1_kernel(
    const float* __restrict__ xr, const float* __restrict__ xi,
    int* __restrict__ idx,
    short* __restrict__ Ar, short* __restrict__ Ai,
    const float* __restrict__ Wr1, const float* __restrict__ Wi1,
    short* __restrict__ W1p)
{
  __shared__ float tr[64][33], ti[64][33];
  int bid = blockIdx.x;
  if (bid < 256) {
    // route: 8 tokens per block, width-32 reduce (r7-proven)
    int tid = threadIdx.x;
    int t = bid * 8 + (tid >> 5);
    int l = tid & 31;
    const float* r  = xr + (size_t)t * FDIM;
    const float* im = xi + (size_t)t * FDIM;
    float sc = 0.f, ss = 0.f;
    #pragma unroll
    for (int p = 0; p < 4; ++p) {
      int f = p * 128 + l * 4;
      float4 a4 = *(const float4*)(r + f);
      float4 b4 = *(const float4*)(im + f);
      float av[4] = {a4.x, a4.y, a4.z, a4.w};
      float bv[4] = {b4.x, b4.y, b4.z, b4.w};
      #pragma unroll
      for (int j = 0; j < 4; ++j) {
        float h2 = av[j] * av[j] + bv[j] * bv[j];
        if (h2 > 0.f) {
          float rs = rsqrtf(h2);
          sc += av[j] * rs;
          ss += bv[j] * rs;
        } else {
          sc += 1.f;   // atan2(0,0)=0 -> cos=1, sin=0
        }
      }
    }
    #pragma unroll
    for (int off = 16; off > 0; off >>= 1) {
      sc += __shfl_down(sc, off, 32);
      ss += __shfl_down(ss, off, 32);
    }
    if (l == 0) {
      float phase = atan2f(ss, sc);
      float norm = (phase + PI_F) / (2.f * PI_F);
      int e = (int)floorf(norm * (float)NEXP);
      e = min(max(e, 0), NEXP - 1);
      idx[t] = e;
    }
  } else if (bid < 256 + 1024) {
    // pack x -> bf16 planes in TOKEN order (no perm dependency)
    int gid = (bid - 256) * 256 + threadIdx.x;   // 1024 blocks x 256
    int i = gid >> 7;
    int c4 = (gid & 127) * 4;
    float4 r = *(const float4*)(xr + (size_t)i * FDIM + c4);
    float4 m = *(const float4*)(xi + (size_t)i * FDIM + c4);
    unsigned short orr[4] = { f2bf(r.x), f2bf(r.y), f2bf(r.z), f2bf(r.w) };
    unsigned short oii[4] = { f2bf(m.x), f2bf(m.y), f2bf(m.z), f2bf(m.w) };
    *(int2*)(Ar + (size_t)i * FDIM + c4) = *(const int2*)orr;
    *(int2*)(Ai + (size_t)i * FDIM + c4) = *(const int2*)oii;
  } else {
    pack_w2x<FDIM, HDIM>(Wr1, Wi1, W1p, bid - 1280, tr, ti);
  }
}

// deterministic scatter (r19-proven): computes counts + offs + perm + rexp
__global__ __launch_bounds__(256) void scatter_kernel(
    const int* __restrict__ idx, int* __restrict__ counts,
    int* __restrict__ offs, int* __restrict__ perm, int* __restrict__ rexp)
{
  __shared__ int base_e[NEXP];
  __shared__ int totals[NEXP];
  __shared__ int tcnt[256][NEXP];
  int tid = threadIdx.x;
  int t0 = tid * 8;
  int eo[8];
  int loc[NEXP];
  #pragma unroll
  for (int e = 0; e < NEXP; ++e) loc[e] = 0;
  #pragma unroll
  for (int j = 0; j < 8; ++j) { eo[j] = idx[t0 + j]; loc[eo[j]]++; }
  #pragma unroll
  for (int e = 0; e < NEXP; ++e) tcnt[tid][e] = loc[e];
  __syncthreads();
  if (tid < NEXP) {
    int e = tid, run = 0;
    for (int i = 0; i < 256; ++i) { int v = tcnt[i][e]; tcnt[i][e] = run; run += v; }
    totals[e] = run;
    counts[e] = run;
  }
  __syncthreads();
  if (tid == 0) {
    int acc = 0;
    for (int e = 0; e < NEXP; ++e) { base_e[e] = acc; offs[e] = acc; acc += totals[e]; }
  }
  __syncthreads();
  #pragma unroll
  for (int e = 0; e < NEXP; ++e) loc[e] = base_e[e] + tcnt[tid][e];
  #pragma unroll
  for (int j = 0; j < 8; ++j) {
    int e = eo[j];
    int pos = loc[e]++;
    perm[pos] = t0 + j;
    rexp[pos] = e;
  }
}

// ---------------- plane-separated complex MFMA grouped GEMM body ------------
// r14-exact schedule + T5 setprio (r24-proven): BM=64 x BNc=64, BK=32, 4 waves,
// 2-buffer 32KB LDS, fully-drained single-__syncthreads-per-step loop.
template<int LDK, int NC, int NX, int NSPLIT, bool IS_L1>
__device__ __forceinline__ void gemm_body(
    int gbid, int xcd, short* AsB, short* WsB,
    const short* __restrict__ Apr, const short* __restrict__ Api,
    const short* __restrict__ Wp,
    const int* __restrict__ counts, const int* __restrict__ offs,
    const int* __restrict__ perm,
    const float* __restrict__ bre, const float* __restrict__ bim,
    const float* __restrict__ mb,
    short* __restrict__ Or, short* __restrict__ Oi,
    unsigned int* __restrict__ P)
{
  constexpr int PBE = NX * 8 * NSPLIT;       // blocks per expert
  constexpr int KCH = LDK / NSPLIT;          // K-chunk
  constexpr int KT = KCH / 32;               // steps
  int virt = xcd * PBE + (gbid >> 3);        // per-XCD expert affinity
  int e = virt / PBE, rem = virt % PBE;
  int x = rem % NX;
  int q = rem / NX;
  int y = q & 7, s = q >> 3;                 // s in [0, NSPLIT)
  int cnt = counts[e];
  int row0 = y * 64;
  if (row0 >= cnt) return;
  int base = offs[e];
  int n0c = x * 64;
  int kbase = s * KCH;

  int tid = threadIdx.x;
  int lane = tid & 63;
  int w = tid >> 6, wm = w >> 1, wn = w & 1;
  int lr = lane & 15, g = lane >> 4;
  int ssw = g ^ ((lr >> 1) & 3);             // swizzled 16B slot for reads

  int srl = tid >> 2, slt = tid & 3;
  int sc = (slt ^ ((srl >> 1) & 3)) * 16;    // pre-swizzled source byte offset
  int arow = min(row0 + srl, cnt - 1);
  size_t asrc;
  if constexpr (IS_L1) asrc = (size_t)perm[base + arow] * LDK + kbase;  // gather
  else                 asrc = (size_t)(base + arow) * LDK + kbase;      // compact
  const char* pAr = (const char*)(Apr + asrc) + sc;
  const char* pAi = (const char*)(Api + asrc) + sc;
  const short* We = Wp + (size_t)e * 2 * NC * LDK;
  const char* pW0 = (const char*)(We + (size_t)(n0c + srl) * LDK + kbase) + sc;
  const char* pW1 = (const char*)(We + ((size_t)NC + n0c + srl) * LDK + kbase) + sc;

  auto STAGE = [&](int buf, int t) {         // 4 gload16 per thread
    char* ab = (char*)AsB + buf * 8192;
    gload16(pAr + t * 64, ab + tid * 16);
    gload16(pAi + t * 64, ab + 4096 + tid * 16);
    char* wb = (char*)WsB + buf * 8192;
    gload16(pW0 + t * 64, wb + tid * 16);
    gload16(pW1 + t * 64, wb + 4096 + tid * 16);
  };

  f32x4 accr[2][2], acci[2][2];
  #pragma unroll
  for (int m = 0; m < 2; ++m)
    #pragma unroll
    for (int n = 0; n < 2; ++n) { accr[m][n] = 0.f; acci[m][n] = 0.f; }

  const bf16x8 SGN = {(short)0x8000, (short)0x8000, (short)0x8000, (short)0x8000,
                      (short)0x8000, (short)0x8000, (short)0x8000, (short)0x8000};

  auto COMPUTE = [&](int buf) {
    const short* Ab = AsB + buf * 4096;
    const short* Wb = WsB + buf * 4096;
    bf16x8 ar[2], ai[2], wr[2], wi[2], wni[2];
    #pragma unroll
    for (int m = 0; m < 2; ++m) {
      int off = (wm * 32 + m * 16 + lr) * 32 + ssw * 8;
      ar[m] = *(const bf16x8*)(Ab + off);
      ai[m] = *(const bf16x8*)(Ab + 2048 + off);
    }
    #pragma unroll
    for (int n = 0; n < 2; ++n) {
      int offw = (wn * 32 + n * 16 + lr) * 32 + ssw * 8;
      wr[n] = *(const bf16x8*)(Wb + offw);
      wi[n] = *(const bf16x8*)(Wb + 2048 + offw);
      wni[n] = wi[n] ^ SGN;
    }
    __builtin_amdgcn_s_setprio(1);           // T5: favor MFMA waves (hint only)
    #pragma unroll
    for (int m = 0; m < 2; ++m)
      #pragma unroll
      for (int n = 0; n < 2; ++n) {
        accr[m][n] = __builtin_amdgcn_mfma_f32_16x16x32_bf16(ar[m], wr[n],  accr[m][n], 0, 0, 0);
        accr[m][n] = __builtin_amdgcn_mfma_f32_16x16x32_bf16(ai[m], wni[n], accr[m][n], 0, 0, 0);
        acci[m][n] = __builtin_amdgcn_mfma_f32_16x16x32_bf16(ar[m], wi[n],  acci[m][n], 0, 0, 0);
        acci[m][n] = __builtin_amdgcn_mfma_f32_16x16x32_bf16(ai[m], wr[n],  acci[m][n], 0, 0, 0);
      }
    __builtin_amdgcn_s_setprio(0);
  };

  STAGE(0, 0);
  int cur = 0;
  for (int t = 0; t < KT; ++t) {
    __syncthreads();                         // full fence: stage of `cur` drained
    if (t + 1 < KT) STAGE(cur ^ 1, t + 1);   // prefetch overlaps COMPUTE(cur)
    COMPUTE(cur);
    cur ^= 1;
  }

  // epilogue
  #pragma unroll
  for (int m = 0; m < 2; ++m) {
    #pragma unroll
    for (int qq = 0; qq < 4; ++qq) {
      int row = row0 + wm * 32 + m * 16 + g * 4 + qq;
      if (row >= cnt) continue;
      #pragma unroll
      for (int n = 0; n < 2; ++n) {
        int c = n0c + wn * 32 + n * 16 + lr;
        if constexpr (IS_L1) {
          float hr = accr[m][n][qq] + bre[e * NC + c];
          float hi = acci[m][n][qq] + bim[e * NC + c];
          float s2 = hr * hr + hi * hi + 1e-10f;
          float rr = __frsqrt_rn(s2);
          float amp = s2 * rr;
          float scl = fmaxf(amp + mb[e * NC + c], 0.f) * rr;
          Or[(size_t)(base + row) * NC + c] = (short)f2bf(hr * scl);
          Oi[(size_t)(base + row) * NC + c] = (short)f2bf(hi * scl);
        } else {
          // packed bf16 partial: lo16 = re, hi16 = im
          unsigned pv = (unsigned)f2bf(accr[m][n][qq])
                      | ((unsigned)f2bf(acci[m][n][qq]) << 16);
          P[((size_t)s * TOKENS + base + row) * 512 + c] = pv;
        }
      }
    }
  }
}

// ---- kernel B (r24-exact): gemm1 (bid%3==0) + pack W2 (4096) ----
__global__ __launch_bounds__(256) void gemm1_packw2_kernel(
    const short* __restrict__ A1r, const short* __restrict__ A1i,
    const short* __restrict__ W1p,
    const int* __restrict__ counts, const int* __restrict__ offs,
    const int* __restrict__ perm,
    const float* __restrict__ br1, const float* __restrict__ bi1,
    const float* __restrict__ mb,
    short* __restrict__ A2r, short* __restrict__ A2i,
    const float* __restrict__ Wr2, const float* __restrict__ Wi2,
    short* __restrict__ W2p)
{
  __shared__ __align__(16) short As[2][2][64][32];   // 16KB
  __shared__ __align__(16) short Ws[2][2][64][32];   // 16KB
  int bid = blockIdx.x;
  int r3 = bid % 3;
  if (r3 == 0) {
    int g = bid / 3;                         // 0..2047, (bid&7, g>>3) bijective
    gemm_body<FDIM, HDIM, 32, 1, true>(g, bid & 7, &As[0][0][0][0], &Ws[0][0][0][0],
        A1r, A1i, W1p, counts, offs, perm, br1, bi1, mb, A2r, A2i, nullptr);
  } else {
    int pb = (bid / 3) * 2 + (r3 - 1);       // 0..4095 bijective
    float (*tr)[33] = (float (*)[33])&As[0][0][0][0];   // 8448B <= 16KB
    float (*ti)[33] = (float (*)[33])&Ws[0][0][0][0];
    pack_w_body64<HDIM, FDIM>(Wr2, Wi2, W2p, pb, tr, ti);
  }
}

// ---------------- standalone gemm2: split-K = 4 (r19-proven) ----------------
__global__ __launch_bounds__(256) void gemm2_kernel(
    const short* __restrict__ A2r, const short* __restrict__ A2i,
    const short* __restrict__ W2p,
    const int* __restrict__ counts, const int* __restrict__ offs,
    unsigned int* __restrict__ P)
{
  __shared__ __align__(16) short As[2][2][64][32];
  __shared__ __align__(16) short Ws[2][2][64][32];
  int bid = blockIdx.x;
  gemm_body<HDIM, FDIM, 8, 4, false>(bid, bid & 7, &As[0][0][0][0], &Ws[0][0][0][0],
      A2r, A2i, W2p, counts, offs, nullptr, nullptr, nullptr, nullptr,
      nullptr, nullptr, P);
}

// ---------------- split-K finalize (4 bf16-packed partials) ----------------
__global__ __launch_bounds__(256) void finalize_kernel(
    const unsigned int* __restrict__ P, const float* __restrict__ br2,
    const float* __restrict__ bi2, const int* __restrict__ perm,
    const int* __restrict__ rexp, float* __restrict__ out)
{
  int gid = blockIdx.x * 256 + threadIdx.x;   // 2048 * 128
  int i = gid >> 7;
  int c4 = (gid & 127) * 4;
  float sr[4] = {0.f, 0.f, 0.f, 0.f}, si[4] = {0.f, 0.f, 0.f, 0.f};
  #pragma unroll
  for (int s = 0; s < 4; ++s) {
    uint4 u = *(const uint4*)(P + ((size_t)s * TOKENS + i) * 512 + c4);
    unsigned uv[4] = {u.x, u.y, u.z, u.w};
    #pragma unroll
    for (int j = 0; j < 4; ++j) {
      sr[j] += __uint_as_float(uv[j] << 16);
      si[j] += __uint_as_float(uv[j] & 0xFFFF0000u);
    }
  }
  int e = rexp[i], tok = perm[i];
  float4 br = *(const float4*)(br2 + e * FDIM + c4);
  float4 bi = *(const float4*)(bi2 + e * FDIM + c4);
  float4 vr = {sr[0] + br.x, sr[1] + br.y, sr[2] + br.z, sr[3] + br.w};
  float4 vi = {si[0] + bi.x, si[1] + bi.y, si[2] + bi.z, si[3] + bi.w};
  *(float4*)(out + (size_t)tok * FDIM + c4) = vr;
  *(float4*)(out + (size_t)TOKENS * FDIM + (size_t)tok * FDIM + c4) = vi;
}

extern "C" void kernel_launch(void* const* d_in, const int* in_sizes, int n_in,
                              void* d_out, int out_size, void* d_ws, size_t ws_size,
                              hipStream_t stream)
{
  const float* xr  = (const float*)d_in[0];
  const float* xi  = (const float*)d_in[1];
  const float* Wr1 = (const float*)d_in[2];
  const float* Wi1 = (const float*)d_in[3];
  const float* br1 = (const float*)d_in[4];
  const float* bi1 = (const float*)d_in[5];
  const float* mb  = (const float*)d_in[6];
  const float* Wr2 = (const float*)d_in[7];
  const float* Wi2 = (const float*)d_in[8];
  const float* br2 = (const float*)d_in[9];
  const float* bi2 = (const float*)d_in[10];
  float* out = (float*)d_out;

  char* ws = (char*)d_ws;
  int* counts = (int*)(ws + 0);
  int* offs   = (int*)(ws + 64);
  int* idx    = (int*)(ws + 128);
  int* perm   = (int*)(ws + 8320);
  int* rexp   = (int*)(ws + 16512);

  size_t off = 32768;
  short* A1r = (short*)(ws + off); off += (size_t)TOKENS * FDIM * 2;
  short* A1i = (short*)(ws + off); off += (size_t)TOKENS * FDIM * 2;
  short* A2r = (short*)(ws + off); off += (size_t)TOKENS * HDIM * 2;
  short* A2i = (short*)(ws + off); off += (size_t)TOKENS * HDIM * 2;
  short* W1p = (short*)(ws + off); off += (size_t)NEXP * 2 * HDIM * FDIM * 2;
  short* W2p = (short*)(ws + off); off += (size_t)NEXP * 2 * FDIM * HDIM * 2;
  unsigned int* P = (unsigned int*)(ws + off);   // 4 x 2048 x 512 uints = 16MB

  // A: route (256) + pack_x token-order (1024) + W1 pack (2048), all parallel
  route_packx_w1_kernel<<<256 + 1024 + 2048, 256, 0, stream>>>(
      xr, xi, idx, A1r, A1i, Wr1, Wi1, W1p);
  // scatter computes counts + offs + perm + rexp from idx
  scatter_kernel<<<1, 256, 0, stream>>>(idx, counts, offs, perm, rexp);

  // B: gemm1 (perm-gather A1, bias+ModReLU fused) concurrent with W2 pack
  gemm1_packw2_kernel<<<6144, 256, 0, stream>>>(
      A1r, A1i, W1p, counts, offs, perm, br1, bi1, mb, A2r, A2i, Wr2, Wi2, W2p);
  // layer2: K=2048 split 4x512 -> packed bf16 partials
  gemm2_kernel<<<2048, 256, 0, stream>>>(A2r, A2i, W2p, counts, offs, P);

  finalize_kernel<<<TOKENS * 128 / 256, 256, 0, stream>>>(
      P, br2, bi2, perm, rexp, out);
}